// Round 1
// baseline (38.330 us; speedup 1.0000x reference)
//
#include <hip/hip_runtime.h>

// Degree-2 Taylor causal linear attention, collapsed to quadratic attention:
//   Y_S[b,h,s,:] = (1/64) * sum_{s'<=s} (Q[s]·K[s'])^2 * V[s']
//   Y_Z[b,h,s]   = (1/64) * sum_{s'<=s} (Q[s]·K[s'])^2
// B=1, H=8, S=512, DK=32, DV=64, fp32.

constexpr int H_  = 8;
constexpr int S_  = 512;
constexpr int DK  = 32;
constexpr int DV  = 64;
constexpr int QB  = 16;   // queries per block
constexpr int KB  = 32;   // keys per tile
constexpr float ALPHA = 1.0f / 64.0f;

__global__ __launch_bounds__(256, 1) void taylor_attn(
    const float* __restrict__ Qg, const float* __restrict__ Kg,
    const float* __restrict__ Vg, float* __restrict__ out)
{
    const int bid = blockIdx.x;
    const int qt  = bid & (S_/QB - 1);   // 0..31 query tile
    const int h   = bid >> 5;            // 0..7 head
    const int t   = threadIdx.x;

    __shared__ float Kt[DK][KB + 2];     // K tile transposed, padded (conflict-free)
    __shared__ float Vs[KB][DV];         // V tile
    __shared__ float Ss[QB][KB + 2];     // score tile, padded

    // ---- score-phase thread mapping: (query row sq, key-pair base sj) ----
    const int sq = t >> 4;           // 0..15
    const int sj = (t & 15) * 2;     // 0,2,..,30

    // Q row for the score phase lives in registers (reused across all key tiles)
    float qreg[DK];
    {
        const int gq = qt * QB + sq;
        const float* qrow = Qg + (size_t)(h * S_ + gq) * DK;
        #pragma unroll
        for (int d4 = 0; d4 < DK; d4 += 4) {
            float4 v = *reinterpret_cast<const float4*>(qrow + d4);
            qreg[d4 + 0] = v.x; qreg[d4 + 1] = v.y;
            qreg[d4 + 2] = v.z; qreg[d4 + 3] = v.w;
        }
    }

    // ---- accumulate-phase thread mapping: (dval dim ad, query subgroup aq) ----
    const int ad = t & 63;           // 0..63 (lane == d_val dim, conflict-free Vs reads)
    const int aq = t >> 6;           // 0..3  (wave id == query subgroup)
    float acc[4] = {0.f, 0.f, 0.f, 0.f};
    float zacc = 0.f;

    const int last_q = qt * QB + QB - 1;
    const int nkt    = last_q / KB + 1;   // causal: only key tiles <= query range

    for (int kt = 0; kt < nkt; ++kt) {
        // ---- stage K (transposed) and V tiles into LDS ----
        {
            const int row  = t >> 3;        // 0..31 key row
            const int col  = (t & 7) * 4;   // 0..28 key dim base
            const float* krow = Kg + (size_t)(h * S_ + kt * KB + row) * DK + col;
            float4 kv = *reinterpret_cast<const float4*>(krow);
            Kt[col + 0][row] = kv.x;
            Kt[col + 1][row] = kv.y;
            Kt[col + 2][row] = kv.z;
            Kt[col + 3][row] = kv.w;

            const int vcol = (t & 7) * 8;   // 0..56
            const float* vrow = Vg + (size_t)(h * S_ + kt * KB + row) * DV + vcol;
            float4 v0 = *reinterpret_cast<const float4*>(vrow);
            float4 v1 = *reinterpret_cast<const float4*>(vrow + 4);
            *reinterpret_cast<float4*>(&Vs[row][vcol])     = v0;
            *reinterpret_cast<float4*>(&Vs[row][vcol + 4]) = v1;
        }
        __syncthreads();

        // ---- scores: s(q, j) = (Q[q]·K[j])^2 * ALPHA, causal-masked ----
        {
            float s0 = 0.f, s1 = 0.f;
            #pragma unroll
            for (int d = 0; d < DK; ++d) {
                float2 kk = *reinterpret_cast<const float2*>(&Kt[d][sj]);
                s0 = fmaf(qreg[d], kk.x, s0);
                s1 = fmaf(qreg[d], kk.y, s1);
            }
            const int gq  = qt * QB + sq;
            const int gk0 = kt * KB + sj;
            s0 = (gk0     <= gq) ? s0 * s0 * ALPHA : 0.f;
            s1 = (gk0 + 1 <= gq) ? s1 * s1 * ALPHA : 0.f;
            *reinterpret_cast<float2*>(&Ss[sq][sj]) = make_float2(s0, s1);
        }
        __syncthreads();

        // ---- accumulate: acc[qq] += S[q][j] * V[j][ad] ----
        #pragma unroll 8
        for (int j = 0; j < KB; ++j) {
            float v = Vs[j][ad];
            #pragma unroll
            for (int qq = 0; qq < 4; ++qq)
                acc[qq] = fmaf(Ss[aq * 4 + qq][j], v, acc[qq]);
        }
        if (t < QB) {
            #pragma unroll 8
            for (int j = 0; j < KB; ++j) zacc += Ss[t][j];
        }
        __syncthreads();   // before next tile overwrites LDS
    }

    // ---- store Y_S ----
    #pragma unroll
    for (int qq = 0; qq < 4; ++qq) {
        const int gq = qt * QB + aq * 4 + qq;
        out[(size_t)(h * S_ + gq) * DV + ad] = acc[qq];
    }
    // ---- store Y_Z (after Y_S block: H*S*DV floats) ----
    if (t < QB) {
        const int gq = qt * QB + t;
        out[(size_t)(H_ * S_ * DV) + h * S_ + gq] = zacc;
    }
}

extern "C" void kernel_launch(void* const* d_in, const int* in_sizes, int n_in,
                              void* d_out, int out_size, void* d_ws, size_t ws_size,
                              hipStream_t stream) {
    const float* Q = (const float*)d_in[0];
    const float* K = (const float*)d_in[1];
    const float* V = (const float*)d_in[2];
    // d_in[3] = M (monomial indices), d_in[4] = C (coeffs): folded into the
    // (q·k)^2 identity; d_in[5] = continue_prev (always 0) — all unused.
    float* out = (float*)d_out;

    dim3 grid(H_ * (S_ / QB));   // 256 blocks
    dim3 block(256);
    taylor_attn<<<grid, block, 0, stream>>>(Q, K, V, out);
}

// Round 2
// 33.908 us; speedup vs baseline: 1.1304x; 1.1304x over previous
//
#include <hip/hip_runtime.h>

// Degree-2 Taylor causal linear attention, collapsed to quadratic attention:
//   Y_S[b,h,s,:] = (1/64) * sum_{s'<=s} (Q[s]·K[s'])^2 * V[s']
//   Y_Z[b,h,s]   = (1/64) * sum_{s'<=s} (Q[s]·K[s'])^2
// B=1, H=8, S=512, DK=32, DV=64, fp32.
//
// Structure: one 64-lane wave per (head, query). No LDS, no barriers.
//   Phase A (lane = key): dot(Q[q], K[k])^2 * ALPHA, causal-masked.
//   Phase B (lane = d_val): acc += readlane(s, kk) * V[k, lane].
// Heavy queries (large q) in low block IDs so they dispatch first.

constexpr int H_  = 8;
constexpr int S_  = 512;
constexpr int DK  = 32;
constexpr int DV  = 64;
constexpr float ALPHA = 1.0f / 64.0f;

__global__ __launch_bounds__(256) void taylor_attn_wpq(
    const float* __restrict__ Qg, const float* __restrict__ Kg,
    const float* __restrict__ Vg, float* __restrict__ out)
{
    const int w  = threadIdx.x >> 6;          // wave within block: 0..3
    const int l  = threadIdx.x & 63;          // lane
    const int gw = blockIdx.x * 4 + w;        // global wave id: 0..4095
    const int h  = gw & 7;                    // head
    const int q  = S_ - 1 - (gw >> 3);        // query row; deep queries first

    // Q row in registers (wave-uniform values, 32 VGPRs)
    float qreg[DK];
    {
        const float* qrow = Qg + (size_t)(h * S_ + q) * DK;
        #pragma unroll
        for (int d4 = 0; d4 < DK; d4 += 4) {
            float4 v = *reinterpret_cast<const float4*>(qrow + d4);
            qreg[d4 + 0] = v.x; qreg[d4 + 1] = v.y;
            qreg[d4 + 2] = v.z; qreg[d4 + 3] = v.w;
        }
    }

    const float* Kh = Kg + (size_t)h * S_ * DK;
    const float* Vh = Vg + (size_t)h * S_ * DV;

    float acc  = 0.f;   // Y_S[q, lane]
    float zacc = 0.f;   // partial Y_Z (lane-local, reduced at end)

    const int nc = (q >> 6) + 1;              // causal chunk count: 1..8
    for (int c = 0; c < nc; ++c) {
        const int k = (c << 6) + l;           // this lane's key row

        // ---- Phase A: s_l = (Q[q] . K[k])^2 * ALPHA, masked ----
        float dot = 0.f;
        {
            const float* krow = Kh + (size_t)k * DK;
            #pragma unroll
            for (int d4 = 0; d4 < DK; d4 += 4) {
                float4 kv = *reinterpret_cast<const float4*>(krow + d4);
                dot = fmaf(qreg[d4 + 0], kv.x, dot);
                dot = fmaf(qreg[d4 + 1], kv.y, dot);
                dot = fmaf(qreg[d4 + 2], kv.z, dot);
                dot = fmaf(qreg[d4 + 3], kv.w, dot);
            }
        }
        float s = (k <= q) ? dot * dot * ALPHA : 0.f;
        zacc += s;

        // ---- Phase B: acc += s_kk * V[c*64+kk, lane], s broadcast via readlane ----
        const uint32_t sbits = __float_as_uint(s);
        const float* vbase = Vh + (size_t)(c << 6) * DV + l;
        #pragma unroll
        for (int kk = 0; kk < 64; ++kk) {
            float sk = __uint_as_float(__builtin_amdgcn_readlane(sbits, kk));
            acc = fmaf(sk, vbase[(size_t)kk * DV], acc);
        }
    }

    // ---- store Y_S (coalesced 256B per wave) ----
    out[(size_t)(h * S_ + q) * DV + l] = acc;

    // ---- Y_Z: reduce zacc across the 64 lanes, lane 0 writes ----
    #pragma unroll
    for (int off = 32; off; off >>= 1)
        zacc += __shfl_xor(zacc, off);
    if (l == 0)
        out[(size_t)(H_ * S_ * DV) + h * S_ + q] = zacc;
}

extern "C" void kernel_launch(void* const* d_in, const int* in_sizes, int n_in,
                              void* d_out, int out_size, void* d_ws, size_t ws_size,
                              hipStream_t stream) {
    const float* Q = (const float*)d_in[0];
    const float* K = (const float*)d_in[1];
    const float* V = (const float*)d_in[2];
    // d_in[3]=M, d_in[4]=C folded into the (q.k)^2 identity; d_in[5]=continue_prev==0.
    float* out = (float*)d_out;

    dim3 grid(H_ * S_ / 4);   // 1024 blocks, 4 waves (4 queries) each
    dim3 block(256);
    taylor_attn_wpq<<<grid, block, 0, stream>>>(Q, K, V, out);
}

// Round 3
// 33.898 us; speedup vs baseline: 1.1308x; 1.0003x over previous
//
#include <hip/hip_runtime.h>

// Degree-2 Taylor causal linear attention, collapsed to quadratic attention:
//   Y_S[b,h,s,:] = (1/64) * sum_{s'<=s} (Q[s]·K[s'])^2 * V[s']
//   Y_Z[b,h,s]   = (1/64) * sum_{s'<=s} (Q[s]·K[s'])^2
// B=1, H=8, S=512, DK=32, DV=64, fp32.
//
// One 64-lane wave per (head, query); block = 4 consecutive queries of the
// SAME head (L1 sharing), head = blockIdx&7 (pins each head to one XCD's L2).
// Phase A (lane = key): s_l = (Q[q]·K[c*64+l])^2 * ALPHA, causal-masked.
// Phase B (lane = (keygroup g, dv4)): 16x { 1 coalesced float4 V load +
//   1 shfl-broadcast of s + 4 fmac } per 64-key chunk.

constexpr int H_  = 8;
constexpr int S_  = 512;
constexpr int DK  = 32;
constexpr int DV  = 64;
constexpr float ALPHA = 1.0f / 64.0f;

__global__ __launch_bounds__(256) void taylor_attn_v3(
    const float* __restrict__ Qg, const float* __restrict__ Kg,
    const float* __restrict__ Vg, float* __restrict__ out)
{
    const int w = threadIdx.x >> 6;           // wave in block: 0..3
    const int l = threadIdx.x & 63;           // lane
    const int b = blockIdx.x;
    const int h = b & 7;                      // head; b%8 round-robins XCDs
    const int q = (S_ - 1 - ((b >> 3) << 2)) - w;  // 4 consecutive q, deep first

    // Q row in registers
    float qreg[DK];
    {
        const float* qrow = Qg + (size_t)(h * S_ + q) * DK;
        #pragma unroll
        for (int d4 = 0; d4 < DK; d4 += 4) {
            float4 v = *reinterpret_cast<const float4*>(qrow + d4);
            qreg[d4 + 0] = v.x; qreg[d4 + 1] = v.y;
            qreg[d4 + 2] = v.z; qreg[d4 + 3] = v.w;
        }
    }

    const float* Kh = Kg + (size_t)h * S_ * DK;
    const float* Vh = Vg + (size_t)h * S_ * DV;

    // phase-B lane mapping
    const int g  = l >> 4;        // key group 0..3 (key ≡ g mod 4 within chunk)
    const int d4 = (l & 15) * 4;  // dval base

    float4 acc = make_float4(0.f, 0.f, 0.f, 0.f);  // partial Y_S[q, d4..d4+3] over keys≡g
    float  zacc = 0.f;                              // partial Y_Z (lane=key)

    const int nc = (q >> 6) + 1;  // causal chunk count 1..8
    for (int c = 0; c < nc; ++c) {
        // ---- Phase A: lane = key c*64+l ----
        float dot0 = 0.f, dot1 = 0.f;
        {
            const float* krow = Kh + (size_t)(c * 64 + l) * DK;
            #pragma unroll
            for (int d8 = 0; d8 < DK; d8 += 8) {
                float4 k0 = *reinterpret_cast<const float4*>(krow + d8);
                float4 k1 = *reinterpret_cast<const float4*>(krow + d8 + 4);
                dot0 = fmaf(qreg[d8 + 0], k0.x, dot0);
                dot0 = fmaf(qreg[d8 + 1], k0.y, dot0);
                dot0 = fmaf(qreg[d8 + 2], k0.z, dot0);
                dot0 = fmaf(qreg[d8 + 3], k0.w, dot0);
                dot1 = fmaf(qreg[d8 + 4], k1.x, dot1);
                dot1 = fmaf(qreg[d8 + 5], k1.y, dot1);
                dot1 = fmaf(qreg[d8 + 6], k1.z, dot1);
                dot1 = fmaf(qreg[d8 + 7], k1.w, dot1);
            }
        }
        const float dot = dot0 + dot1;
        const float s = ((c * 64 + l) <= q) ? dot * dot * ALPHA : 0.f;
        zacc += s;

        // ---- Phase B: 16 coalesced float4 loads of V, shfl-broadcast s ----
        // iter i handles key kk = c*64 + 4*i + g; lanes cover V[kk][d4..d4+3].
        const float* vbase = Vh + (size_t)(c * 64 + g) * DV + d4;
        #pragma unroll
        for (int i = 0; i < 16; ++i) {
            float4 vv = *reinterpret_cast<const float4*>(vbase + (size_t)(4 * i) * DV);
            float si = __shfl(s, 4 * i + g);
            acc.x = fmaf(si, vv.x, acc.x);
            acc.y = fmaf(si, vv.y, acc.y);
            acc.z = fmaf(si, vv.z, acc.z);
            acc.w = fmaf(si, vv.w, acc.w);
        }
    }

    // ---- reduce acc over the 4 key groups (lanes l, l^16, l^32, l^48) ----
    acc.x += __shfl_xor(acc.x, 16); acc.y += __shfl_xor(acc.y, 16);
    acc.z += __shfl_xor(acc.z, 16); acc.w += __shfl_xor(acc.w, 16);
    acc.x += __shfl_xor(acc.x, 32); acc.y += __shfl_xor(acc.y, 32);
    acc.z += __shfl_xor(acc.z, 32); acc.w += __shfl_xor(acc.w, 32);

    if (l < 16) {
        float4* o = reinterpret_cast<float4*>(out + (size_t)(h * S_ + q) * DV + l * 4);
        *o = acc;
    }

    // ---- Y_Z: butterfly-reduce zacc, lane 0 writes ----
    #pragma unroll
    for (int off = 32; off; off >>= 1)
        zacc += __shfl_xor(zacc, off);
    if (l == 0)
        out[(size_t)(H_ * S_ * DV) + h * S_ + q] = zacc;
}

extern "C" void kernel_launch(void* const* d_in, const int* in_sizes, int n_in,
                              void* d_out, int out_size, void* d_ws, size_t ws_size,
                              hipStream_t stream) {
    const float* Q = (const float*)d_in[0];
    const float* K = (const float*)d_in[1];
    const float* V = (const float*)d_in[2];
    // d_in[3]=M, d_in[4]=C folded into the (q.k)^2 identity; d_in[5]=continue_prev==0.
    float* out = (float*)d_out;

    dim3 grid(H_ * S_ / 4);   // 1024 blocks: 4 consecutive queries, one head each
    dim3 block(256);
    taylor_attn_v3<<<grid, block, 0, stream>>>(Q, K, V, out);
}

// Round 4
// 29.684 us; speedup vs baseline: 1.2913x; 1.1420x over previous
//
#include <hip/hip_runtime.h>

// Degree-2 Taylor causal linear attention == causal quadratic attention:
//   Y_S[h,s,:] = (1/64) * sum_{s'<=s} (Q[s]·K[s'])^2 * V[s']
//   Y_Z[h,s]   = (1/64) * sum_{s'<=s} (Q[s]·K[s'])^2
// H=8, S=512, DK=32, DV=64, fp32 in/out.
//
// MFMA formulation (bf16, split-precision for Q,K):
//   S^T[k][q] = mfma_16x16x32( A=K-tile[16k x 32d], B=Q^T[32d x 16q] )
//     3 MFMAs per tile: Kh*Qh + Kh*Ql + Kl*Qh  (error ~2^-16 rel)
//   s = dot^2/64 (f32), causal mask, Y_Z accum; S -> bf16 -> LDS
//   Y[q][d]  = mfma_16x16x32( A=S[16q x 32k], B=V[32k x 16d] )
// Kernel 1 converts Q/K to hi/lo bf16 and V to chunk-transposed bf16 in d_ws.
// Kernel 2: 128 blocks x 1 wave (8 heads x 16 q-tiles of 32q), barrier-free,
// LDS staging with XOR-swizzled 16B granules for conflict-free b128 reads.

typedef __attribute__((ext_vector_type(8))) short short8;   // 8 bf16 (4 VGPR)
typedef __attribute__((ext_vector_type(4))) float floatx4;  // MFMA C/D

constexpr int H_ = 8, S_ = 512, DK = 32, DV = 64;
constexpr float ALPHA = 1.0f / 64.0f;

// ws layout in ushort elems:
//   Qhi @ 0        (131072)   Qlo @ 131072
//   Khi @ 262144              Klo @ 393216
//   Vt  @ 524288   [h][chunk][64 d][64 k] bf16 (chunk-transposed V)
constexpr int OFF_QLO = 131072, OFF_KHI = 262144, OFF_KLO = 393216, OFF_VT = 524288;

__device__ __forceinline__ unsigned short f2bf(float x) {
    unsigned int u = __float_as_uint(x);
    u += 0x7FFFu + ((u >> 16) & 1u);          // round-to-nearest-even
    return (unsigned short)(u >> 16);
}
__device__ __forceinline__ float bf2f(unsigned short h) {
    return __uint_as_float(((unsigned int)h) << 16);
}

// ---- Kernel 1: convert Q,K (split hi/lo) + transpose-convert V ----
__global__ __launch_bounds__(256) void convert_kern(
    const float* __restrict__ Q, const float* __restrict__ K,
    const float* __restrict__ V, unsigned short* __restrict__ ws)
{
    const int b = blockIdx.x;
    if (b < 128) {
        // Q,K: 131072 floats each; 128 blocks * 256 thr * 4 floats
        const int i4 = b * 256 + threadIdx.x;
        float4 qv = ((const float4*)Q)[i4];
        float4 kv = ((const float4*)K)[i4];
        float qa[4] = {qv.x, qv.y, qv.z, qv.w};
        float ka[4] = {kv.x, kv.y, kv.z, kv.w};
        unsigned short qh[4], ql[4], kh[4], kl[4];
        #pragma unroll
        for (int j = 0; j < 4; ++j) {
            unsigned short hh = f2bf(qa[j]);
            qh[j] = hh; ql[j] = f2bf(qa[j] - bf2f(hh));
            hh = f2bf(ka[j]);
            kh[j] = hh; kl[j] = f2bf(ka[j] - bf2f(hh));
        }
        ((ushort4*)(ws))[i4]           = make_ushort4(qh[0], qh[1], qh[2], qh[3]);
        ((ushort4*)(ws + OFF_QLO))[i4] = make_ushort4(ql[0], ql[1], ql[2], ql[3]);
        ((ushort4*)(ws + OFF_KHI))[i4] = make_ushort4(kh[0], kh[1], kh[2], kh[3]);
        ((ushort4*)(ws + OFF_KLO))[i4] = make_ushort4(kl[0], kl[1], kl[2], kl[3]);
    } else {
        // V transpose: block handles one (head, 64-key chunk): [64k][64d] -> [64d][64k]
        __shared__ float T[64][65];
        const int bb = b - 128;
        const int h = bb >> 3, sc = bb & 7;
        const float* Vb = V + ((size_t)(h * S_) + sc * 64) * DV;
        #pragma unroll
        for (int i = 0; i < 4; ++i) {
            int idx4 = threadIdx.x + 256 * i;     // 0..1023 float4 chunks
            int s = idx4 >> 4, c4 = (idx4 & 15) * 4;
            float4 v = *(const float4*)(Vb + s * DV + c4);
            T[s][c4] = v.x; T[s][c4 + 1] = v.y; T[s][c4 + 2] = v.z; T[s][c4 + 3] = v.w;
        }
        __syncthreads();
        const int w = threadIdx.x >> 6, l = threadIdx.x & 63;
        unsigned short* Vt = ws + OFF_VT + (size_t)((h * 8 + sc) * 64) * 64;
        #pragma unroll
        for (int p = 0; p < 16; ++p) {
            int d = w * 16 + p;
            Vt[d * 64 + l] = f2bf(T[l][d]);       // coalesced 128B stores
        }
    }
}

// ---- Kernel 2: main MFMA attention. 1 wave/block, 32 queries/block ----
__global__ __launch_bounds__(64) void taylor_mfma(
    const unsigned short* __restrict__ ws, float* __restrict__ out)
{
    const int l = threadIdx.x;                  // lane 0..63
    const int h = blockIdx.x & 7;
    const int qt = 15 - (blockIdx.x >> 3);      // deep q-tiles dispatch first
    const int qbase = qt * 32;
    const int nc = (qt >> 1) + 1;               // causal 64-key chunks
    const int g = l >> 4, r15 = l & 15;

    __shared__ alignas(16) unsigned short Khs[64 * 40];  // [64k][32d], 80B pitch
    __shared__ alignas(16) unsigned short Kls[64 * 40];
    __shared__ alignas(16) unsigned short Vts[64 * 64];  // [64d][64k], swizzled
    __shared__ alignas(16) unsigned short Ssm[32 * 64];  // [32q][64k], swizzled

    const unsigned short* wsQhi = ws;
    const unsigned short* wsQlo = ws + OFF_QLO;
    const unsigned short* wsKhi = ws + OFF_KHI;
    const unsigned short* wsKlo = ws + OFF_KLO;
    const unsigned short* wsVt  = ws + OFF_VT;

    // Q B-fragments, persistent across chunks. B[k=d][n=q]: lane: q=l&15, d=(l>>4)*8+j
    short8 qBh[2], qBl[2];
    #pragma unroll
    for (int qtile = 0; qtile < 2; ++qtile) {
        int q = qbase + qtile * 16 + r15;
        qBh[qtile] = ((const short8*)(wsQhi + (h * S_ + q) * DK))[g];
        qBl[qtile] = ((const short8*)(wsQlo + (h * S_ + q) * DK))[g];
    }

    int4 kh[4], kl[4], vv[8];                   // chunk prefetch registers
    auto loadchunk = [&](int c) {
        const int4* pkh = (const int4*)(wsKhi + h * 16384 + c * 2048);
        const int4* pkl = (const int4*)(wsKlo + h * 16384 + c * 2048);
        #pragma unroll
        for (int i = 0; i < 4; ++i) { kh[i] = pkh[i * 64 + l]; kl[i] = pkl[i * 64 + l]; }
        const int4* pv = (const int4*)(wsVt + (h * 8 + c) * 4096);
        #pragma unroll
        for (int i = 0; i < 8; ++i) vv[i] = pv[i * 64 + l];
    };

    floatx4 acc[2][4] = {};                     // Y tiles: [qtile][dtile]
    float zacc[2] = {0.f, 0.f};

    loadchunk(0);
    for (int c = 0; c < nc; ++c) {
        // stage chunk c (waits on vmcnt via register use)
        #pragma unroll
        for (int i = 0; i < 4; ++i) {
            int G = i * 64 + l;
            *(int4*)((char*)Khs + (G >> 2) * 80 + (G & 3) * 16) = kh[i];
            *(int4*)((char*)Kls + (G >> 2) * 80 + (G & 3) * 16) = kl[i];
        }
        #pragma unroll
        for (int i = 0; i < 8; ++i) {
            int G = i * 64 + l;
            int d = G >> 3, gg = G & 7;
            *(int4*)((char*)Vts + d * 128 + ((gg ^ (d & 7)) << 4)) = vv[i];
        }
        if (c + 1 < nc) loadchunk(c + 1);       // prefetch next chunk

        const bool last = (c == nc - 1);
        // ---- QK^T: S^T[k][q], 4 ktiles x 2 qtiles, split-bf16 (3 MFMAs) ----
        #pragma unroll
        for (int ktile = 0; ktile < 4; ++ktile) {
            short8 kAh = *(const short8*)((const char*)Khs + (ktile * 16 + r15) * 80 + g * 16);
            short8 kAl = *(const short8*)((const char*)Kls + (ktile * 16 + r15) * 80 + g * 16);
            #pragma unroll
            for (int qtile = 0; qtile < 2; ++qtile) {
                floatx4 cc = {0.f, 0.f, 0.f, 0.f};
                cc = __builtin_amdgcn_mfma_f32_16x16x32_bf16(kAh, qBh[qtile], cc, 0, 0, 0);
                cc = __builtin_amdgcn_mfma_f32_16x16x32_bf16(kAh, qBl[qtile], cc, 0, 0, 0);
                cc = __builtin_amdgcn_mfma_f32_16x16x32_bf16(kAl, qBh[qtile], cc, 0, 0, 0);
                // lane: q = col = l&15 (+tiles), k = row = (l>>4)*4 + r (+tiles)
                const int qg = qbase + qtile * 16 + r15;
                const int kb = c * 64 + ktile * 16 + g * 4;
                float s[4];
                #pragma unroll
                for (int rr = 0; rr < 4; ++rr) {
                    float dot = cc[rr];
                    float sv = dot * dot * ALPHA;
                    if (last && (kb + rr > qg)) sv = 0.f;
                    s[rr] = sv;
                }
                zacc[qtile] += (s[0] + s[1]) + (s[2] + s[3]);
                unsigned int p0 = (unsigned int)f2bf(s[0]) | ((unsigned int)f2bf(s[1]) << 16);
                unsigned int p1 = (unsigned int)f2bf(s[2]) | ((unsigned int)f2bf(s[3]) << 16);
                const int qrow = qtile * 16 + r15;
                const int k0 = ktile * 16 + g * 4;
                const int byte = qrow * 128 + (((k0 >> 3) ^ (qrow & 7)) << 4) + ((k0 & 7) * 2);
                *(unsigned int*)((char*)Ssm + byte)     = p0;
                *(unsigned int*)((char*)Ssm + byte + 4) = p1;
            }
        }
        // ---- PV: Y[q][d] += S[q][32k-chunk] * V[32k][d] ----
        #pragma unroll
        for (int kc = 0; kc < 2; ++kc) {
            short8 sA[2];
            #pragma unroll
            for (int qtile = 0; qtile < 2; ++qtile) {
                const int qrow = qtile * 16 + r15;
                const int g16 = kc * 4 + g;
                sA[qtile] = *(const short8*)((const char*)Ssm + qrow * 128 + ((g16 ^ (qrow & 7)) << 4));
            }
            #pragma unroll
            for (int dtile = 0; dtile < 4; ++dtile) {
                const int d = dtile * 16 + r15;
                const int gg = kc * 4 + g;
                short8 vB = *(const short8*)((const char*)Vts + d * 128 + ((gg ^ (d & 7)) << 4));
                acc[0][dtile] = __builtin_amdgcn_mfma_f32_16x16x32_bf16(sA[0], vB, acc[0][dtile], 0, 0, 0);
                acc[1][dtile] = __builtin_amdgcn_mfma_f32_16x16x32_bf16(sA[1], vB, acc[1][dtile], 0, 0, 0);
            }
        }
    }

    // ---- store Y_S: D layout col=l&15 (d), row=(l>>4)*4+rr (q) ----
    #pragma unroll
    for (int qtile = 0; qtile < 2; ++qtile)
        #pragma unroll
        for (int dtile = 0; dtile < 4; ++dtile)
            #pragma unroll
            for (int rr = 0; rr < 4; ++rr) {
                int q = qbase + qtile * 16 + g * 4 + rr;
                int d = dtile * 16 + r15;
                out[(size_t)(h * S_ + q) * DV + d] = acc[qtile][dtile][rr];
            }
    // ---- Y_Z: reduce over the 4 lane-groups (k coverage), write 32 values ----
    #pragma unroll
    for (int qtile = 0; qtile < 2; ++qtile) {
        float z = zacc[qtile];
        z += __shfl_xor(z, 16);
        z += __shfl_xor(z, 32);
        zacc[qtile] = z;
    }
    if (l < 16)       out[(size_t)(H_ * S_ * DV) + h * S_ + qbase + l] = zacc[0];
    else if (l < 32)  out[(size_t)(H_ * S_ * DV) + h * S_ + qbase + 16 + r15] = zacc[1];
}

extern "C" void kernel_launch(void* const* d_in, const int* in_sizes, int n_in,
                              void* d_out, int out_size, void* d_ws, size_t ws_size,
                              hipStream_t stream) {
    const float* Q = (const float*)d_in[0];
    const float* K = (const float*)d_in[1];
    const float* V = (const float*)d_in[2];
    // d_in[3]=M, d_in[4]=C folded into the (q.k)^2 identity; d_in[5]=continue_prev==0.
    unsigned short* ws = (unsigned short*)d_ws;   // needs ~1.6 MB, ws is far larger
    float* out = (float*)d_out;

    convert_kern<<<192, 256, 0, stream>>>(Q, K, V, ws);
    taylor_mfma<<<128, 64, 0, stream>>>(ws, out);
}

// Round 5
// 11.720 us; speedup vs baseline: 3.2706x; 2.5328x over previous
//
#include <hip/hip_runtime.h>

// Degree-2 Taylor causal linear attention == causal quadratic attention:
//   Y_S[h,s,:] = (1/64) * sum_{s'<=s} (Q[s]·K[s'])^2 * V[s']
//   Y_Z[h,s]   = (1/64) * sum_{s'<=s} (Q[s]·K[s'])^2
// H=8, S=512, DK=32, DV=64, fp32 in/out.
//
// Single fused kernel. Block = (head, 32-query tile), 8 waves; WAVE c OWNS
// 64-key CHUNK c (causal: waves c >= nc idle-but-participate in the reduce).
// Each wave: load Q/K fragments straight from f32 global (8 contiguous
// floats/lane -> split hi/lo bf16 in registers; dot error ~2^-16), V
// fragments as 8 stride-DV scalars/lane (plain bf16). 3 MFMAs per QK tile,
// square/scale/mask in f32, S->bf16 via per-wave swizzled LDS, 16 PV MFMAs.
// Cross-wave: acc partials to swizzled LDS, one __syncthreads, tree-sum.

typedef __attribute__((ext_vector_type(8))) short short8;   // 8 bf16
typedef __attribute__((ext_vector_type(4))) float floatx4;  // MFMA C/D

constexpr int H_ = 8, S_ = 512, DK = 32, DV = 64;
constexpr float ALPHA = 1.0f / 64.0f;

__device__ __forceinline__ unsigned short f2bf(float x) {
    unsigned int u = __float_as_uint(x);
    u += 0x7FFFu + ((u >> 16) & 1u);          // round-to-nearest-even
    return (unsigned short)(u >> 16);
}
__device__ __forceinline__ float bf2f(unsigned short h) {
    return __uint_as_float(((unsigned int)h) << 16);
}
// 8 contiguous floats -> split hi/lo bf16 fragments
__device__ __forceinline__ void load_split8(const float* p, short8& hi, short8& lo) {
    float4 a = *(const float4*)p;
    float4 b = *(const float4*)(p + 4);
    float f[8] = {a.x, a.y, a.z, a.w, b.x, b.y, b.z, b.w};
    #pragma unroll
    for (int j = 0; j < 8; ++j) {
        unsigned short h = f2bf(f[j]);
        hi[j] = (short)h;
        lo[j] = (short)f2bf(f[j] - bf2f(h));
    }
}

__global__ __launch_bounds__(512) void taylor_fused(
    const float* __restrict__ Qg, const float* __restrict__ Kg,
    const float* __restrict__ Vg, float* __restrict__ out)
{
    const int t = threadIdx.x;
    const int c = t >> 6;                 // wave id == key chunk id 0..7
    const int l = t & 63;                 // lane
    const int h = blockIdx.x & 7;         // head (spreads XCDs)
    const int qt = 15 - (blockIdx.x >> 3);
    const int qbase = qt * 32;
    const int nc = (qt >> 1) + 1;         // causal chunk count 1..8
    const int g = l >> 4, r15 = l & 15;

    __shared__ alignas(16) char Ssm[8 * 4096];    // per-wave S tile (swizzled)
    __shared__ alignas(16) char Racc[8 * 8192];   // per-wave Y partials
    __shared__ float Zb[8][32];                   // per-wave Y_Z partials

    floatx4 acc[2][4] = {};               // [qtile][dtile]
    float zacc[2] = {0.f, 0.f};

    if (c < nc) {
        const bool last = (c == nc - 1);

        // ---- Q B-fragments (persistent): lane = (q=r15, dgroup=g) ----
        short8 qBh[2], qBl[2];
        #pragma unroll
        for (int qtile = 0; qtile < 2; ++qtile)
            load_split8(Qg + (size_t)(h * S_ + qbase + qtile * 16 + r15) * DK + g * 8,
                        qBh[qtile], qBl[qtile]);

        // ---- V B-fragments: lane holds V[c*64+kc*32+g*8+j][dtile*16+r15] ----
        short8 vB[2][4];
        #pragma unroll
        for (int kc = 0; kc < 2; ++kc)
            #pragma unroll
            for (int dtile = 0; dtile < 4; ++dtile) {
                const float* vp = Vg + (size_t)(h * S_ + c * 64 + kc * 32 + g * 8) * DV
                                     + dtile * 16 + r15;
                #pragma unroll
                for (int j = 0; j < 8; ++j)
                    vB[kc][dtile][j] = (short)f2bf(vp[(size_t)j * DV]);
            }

        char* ssmW = Ssm + c * 4096;

        // ---- QK^T: S^T[k][q], 4 ktiles x 2 qtiles, split-bf16 (3 MFMAs) ----
        #pragma unroll
        for (int ktile = 0; ktile < 4; ++ktile) {
            short8 kAh, kAl;
            load_split8(Kg + (size_t)(h * S_ + c * 64 + ktile * 16 + r15) * DK + g * 8,
                        kAh, kAl);
            #pragma unroll
            for (int qtile = 0; qtile < 2; ++qtile) {
                floatx4 cc_ = {0.f, 0.f, 0.f, 0.f};
                cc_ = __builtin_amdgcn_mfma_f32_16x16x32_bf16(kAh, qBh[qtile], cc_, 0, 0, 0);
                cc_ = __builtin_amdgcn_mfma_f32_16x16x32_bf16(kAh, qBl[qtile], cc_, 0, 0, 0);
                cc_ = __builtin_amdgcn_mfma_f32_16x16x32_bf16(kAl, qBh[qtile], cc_, 0, 0, 0);
                // C layout: q = col = l&15, k = row = g*4 + rr (+ tiles)
                const int qg = qbase + qtile * 16 + r15;
                const int kb = c * 64 + ktile * 16 + g * 4;
                float s[4];
                #pragma unroll
                for (int rr = 0; rr < 4; ++rr) {
                    float sv = cc_[rr] * cc_[rr] * ALPHA;
                    if (last && (kb + rr > qg)) sv = 0.f;
                    s[rr] = sv;
                }
                zacc[qtile] += (s[0] + s[1]) + (s[2] + s[3]);
                unsigned int p0 = (unsigned int)f2bf(s[0]) | ((unsigned int)f2bf(s[1]) << 16);
                unsigned int p1 = (unsigned int)f2bf(s[2]) | ((unsigned int)f2bf(s[3]) << 16);
                const int qrow = qtile * 16 + r15;
                const int k0 = ktile * 16 + g * 4;
                const int byte = qrow * 128 + (((k0 >> 3) ^ (qrow & 7)) << 4) + ((k0 & 7) * 2);
                *(unsigned int*)(ssmW + byte)     = p0;
                *(unsigned int*)(ssmW + byte + 4) = p1;
            }
        }

        // ---- PV: Y[q][d] += S[q][32k] * V[32k][d] ----
        #pragma unroll
        for (int kc = 0; kc < 2; ++kc) {
            short8 sA[2];
            #pragma unroll
            for (int qtile = 0; qtile < 2; ++qtile) {
                const int qrow = qtile * 16 + r15;
                const int g16 = kc * 4 + g;
                sA[qtile] = *(const short8*)(ssmW + qrow * 128 + ((g16 ^ (qrow & 7)) << 4));
            }
            #pragma unroll
            for (int dtile = 0; dtile < 4; ++dtile) {
                acc[0][dtile] = __builtin_amdgcn_mfma_f32_16x16x32_bf16(sA[0], vB[kc][dtile], acc[0][dtile], 0, 0, 0);
                acc[1][dtile] = __builtin_amdgcn_mfma_f32_16x16x32_bf16(sA[1], vB[kc][dtile], acc[1][dtile], 0, 0, 0);
            }
        }

        // zacc: sum over the 4 lane-groups -> every lane has full value
        #pragma unroll
        for (int qtile = 0; qtile < 2; ++qtile) {
            float z = zacc[qtile];
            z += __shfl_xor(z, 16);
            z += __shfl_xor(z, 32);
            zacc[qtile] = z;
        }
    }

    // ---- publish partials (idle waves publish zeros) ----
    {
        char* rb = Racc + c * 8192 + l * 128;
        #pragma unroll
        for (int f = 0; f < 8; ++f) {
            floatx4 a = acc[f >> 2][f & 3];
            *(float4*)(rb + ((f ^ (l & 7)) << 4)) = make_float4(a[0], a[1], a[2], a[3]);
        }
        if (l < 32) Zb[c][l] = (l < 16) ? zacc[0] : zacc[1];
    }
    __syncthreads();

    // ---- cross-wave reduce: thread (c,l) owns fragment f=c of lane l ----
    {
        float4 sum = make_float4(0.f, 0.f, 0.f, 0.f);
        #pragma unroll
        for (int cw = 0; cw < 8; ++cw) {
            float4 v = *(const float4*)(Racc + cw * 8192 + l * 128 + ((c ^ (l & 7)) << 4));
            sum.x += v.x; sum.y += v.y; sum.z += v.z; sum.w += v.w;
        }
        const int qtile = c >> 2, dtile = c & 3;
        const int d = dtile * 16 + r15;
        float sv[4] = {sum.x, sum.y, sum.z, sum.w};
        #pragma unroll
        for (int rr = 0; rr < 4; ++rr) {
            int q = qbase + qtile * 16 + g * 4 + rr;
            out[(size_t)(h * S_ + q) * DV + d] = sv[rr];
        }
    }
    // ---- Y_Z ----
    if (t < 32) {
        float z = 0.f;
        #pragma unroll
        for (int cw = 0; cw < 8; ++cw) z += Zb[cw][t];
        out[(size_t)(H_ * S_ * DV) + h * S_ + qbase + t] = z;
    }
}

extern "C" void kernel_launch(void* const* d_in, const int* in_sizes, int n_in,
                              void* d_out, int out_size, void* d_ws, size_t ws_size,
                              hipStream_t stream) {
    const float* Q = (const float*)d_in[0];
    const float* K = (const float*)d_in[1];
    const float* V = (const float*)d_in[2];
    // d_in[3]=M, d_in[4]=C folded into the (q.k)^2 identity; d_in[5]=continue_prev==0.
    float* out = (float*)d_out;

    taylor_fused<<<128, 512, 0, stream>>>(Q, K, V, out);   // single dispatch
}

// Round 6
// 11.291 us; speedup vs baseline: 3.3948x; 1.0380x over previous
//
#include <hip/hip_runtime.h>
#include <hip/hip_bf16.h>

// Degree-2 Taylor causal linear attention == causal quadratic attention:
//   Y_S[h,s,:] = (1/64) * sum_{s'<=s} (Q[s]·K[s'])^2 * V[s']
//   Y_Z[h,s]   = (1/64) * sum_{s'<=s} (Q[s]·K[s'])^2
// H=8, S=512, DK=32, DV=64, fp32 in/out.
//
// Single fused kernel. Block = (head, 32-query tile), 8 waves; wave c owns
// 64-key chunk c. v6 changes vs v5:
//   - ALL raw f32 global loads issued up-front into registers (latency
//     overlaps the conversion VALU instead of serializing per-use).
//   - bf16 conversion via native packed cast (v_cvt_pk_bf16_f32) instead of
//     4-op manual RTNE: same rounding, ~3x fewer VALU.
//   - Racc cross-wave reduce buffer TRANSPOSED [cw][frag][lane]: both the
//     publish and the reduce are stride-1 -> conflict-free (v5's 128B lane
//     stride made every access 8-way bank-conflicted).

typedef __attribute__((ext_vector_type(8))) short short8;   // 8 bf16
typedef __attribute__((ext_vector_type(4))) float floatx4;  // MFMA C/D

constexpr int H_ = 8, S_ = 512, DK = 32, DV = 64;
constexpr float ALPHA = 1.0f / 64.0f;

// packed f32x2 -> bf16x2 (RTNE), bit-cast to a short2-in-uint
__device__ __forceinline__ unsigned int pk_bf16(float a, float b) {
    __hip_bfloat162 h = __float22bfloat162_rn(make_float2(a, b));
    union { __hip_bfloat162 h2; unsigned int u; } cvt;
    cvt.h2 = h;
    return cvt.u;
}
// split two float4 (8 contiguous values) into hi/lo bf16 fragments
__device__ __forceinline__ void split8_cvt(float4 a, float4 b, short8& hi, short8& lo) {
    float f[8] = {a.x, a.y, a.z, a.w, b.x, b.y, b.z, b.w};
    unsigned int hp[4];
    hp[0] = pk_bf16(f[0], f[1]); hp[1] = pk_bf16(f[2], f[3]);
    hp[2] = pk_bf16(f[4], f[5]); hp[3] = pk_bf16(f[6], f[7]);
    float lo_f[8];
    #pragma unroll
    for (int p = 0; p < 4; ++p) {
        float he = __uint_as_float(hp[p] << 16);            // even elem as f32
        float ho = __uint_as_float(hp[p] & 0xFFFF0000u);    // odd elem as f32
        lo_f[2 * p]     = f[2 * p]     - he;
        lo_f[2 * p + 1] = f[2 * p + 1] - ho;
    }
    unsigned int lp[4];
    lp[0] = pk_bf16(lo_f[0], lo_f[1]); lp[1] = pk_bf16(lo_f[2], lo_f[3]);
    lp[2] = pk_bf16(lo_f[4], lo_f[5]); lp[3] = pk_bf16(lo_f[6], lo_f[7]);
    #pragma unroll
    for (int p = 0; p < 4; ++p) {
        hi[2 * p] = (short)(hp[p] & 0xFFFF); hi[2 * p + 1] = (short)(hp[p] >> 16);
        lo[2 * p] = (short)(lp[p] & 0xFFFF); lo[2 * p + 1] = (short)(lp[p] >> 16);
    }
}

__global__ __launch_bounds__(512) void taylor_fused_v6(
    const float* __restrict__ Qg, const float* __restrict__ Kg,
    const float* __restrict__ Vg, float* __restrict__ out)
{
    const int t = threadIdx.x;
    const int c = t >> 6;                 // wave id == key chunk id 0..7
    const int l = t & 63;                 // lane
    const int h = blockIdx.x & 7;         // head (spreads XCDs)
    const int qt = 15 - (blockIdx.x >> 3);
    const int qbase = qt * 32;
    const int nc = (qt >> 1) + 1;         // causal chunk count 1..8
    const int g = l >> 4, r15 = l & 15;

    __shared__ alignas(16) char Ssm[8 * 4096];        // per-wave S tile (swizzled)
    __shared__ alignas(16) float4 Racc[8][8][64];     // [wave][frag][lane] partials
    __shared__ float Zb[8][32];                       // per-wave Y_Z partials

    floatx4 acc[2][4] = {};               // [qtile][dtile]
    float zacc[2] = {0.f, 0.f};

    if (c < nc) {
        const bool last = (c == nc - 1);

        // ============ issue ALL raw loads up-front ============
        float4 qraw[2][2];                // [qtile][half of 8 dims]
        #pragma unroll
        for (int qtile = 0; qtile < 2; ++qtile) {
            const float* qp = Qg + (size_t)(h * S_ + qbase + qtile * 16 + r15) * DK + g * 8;
            qraw[qtile][0] = *(const float4*)qp;
            qraw[qtile][1] = *(const float4*)(qp + 4);
        }
        float4 kraw[4][2];                // [ktile][half]
        #pragma unroll
        for (int ktile = 0; ktile < 4; ++ktile) {
            const float* kp = Kg + (size_t)(h * S_ + c * 64 + ktile * 16 + r15) * DK + g * 8;
            kraw[ktile][0] = *(const float4*)kp;
            kraw[ktile][1] = *(const float4*)(kp + 4);
        }
        float vraw[2][4][8];              // [kc][dtile][j]: V[c*64+kc*32+g*8+j][dtile*16+r15]
        #pragma unroll
        for (int kc = 0; kc < 2; ++kc)
            #pragma unroll
            for (int dtile = 0; dtile < 4; ++dtile) {
                const float* vp = Vg + (size_t)(h * S_ + c * 64 + kc * 32 + g * 8) * DV
                                     + dtile * 16 + r15;
                #pragma unroll
                for (int j = 0; j < 8; ++j)
                    vraw[kc][dtile][j] = vp[(size_t)j * DV];
            }

        // ============ convert Q fragments ============
        short8 qBh[2], qBl[2];
        #pragma unroll
        for (int qtile = 0; qtile < 2; ++qtile)
            split8_cvt(qraw[qtile][0], qraw[qtile][1], qBh[qtile], qBl[qtile]);

        char* ssmW = Ssm + c * 4096;

        // ============ QK^T: 4 ktiles x 2 qtiles, split-bf16 (3 MFMAs) ============
        #pragma unroll
        for (int ktile = 0; ktile < 4; ++ktile) {
            short8 kAh, kAl;
            split8_cvt(kraw[ktile][0], kraw[ktile][1], kAh, kAl);
            #pragma unroll
            for (int qtile = 0; qtile < 2; ++qtile) {
                floatx4 cc_ = {0.f, 0.f, 0.f, 0.f};
                cc_ = __builtin_amdgcn_mfma_f32_16x16x32_bf16(kAh, qBh[qtile], cc_, 0, 0, 0);
                cc_ = __builtin_amdgcn_mfma_f32_16x16x32_bf16(kAh, qBl[qtile], cc_, 0, 0, 0);
                cc_ = __builtin_amdgcn_mfma_f32_16x16x32_bf16(kAl, qBh[qtile], cc_, 0, 0, 0);
                // C layout: q = col = l&15, k = row = g*4 + rr (+ tiles)
                const int qg = qbase + qtile * 16 + r15;
                const int kb = c * 64 + ktile * 16 + g * 4;
                float s[4];
                #pragma unroll
                for (int rr = 0; rr < 4; ++rr) {
                    float sv = cc_[rr] * cc_[rr] * ALPHA;
                    if (last && (kb + rr > qg)) sv = 0.f;
                    s[rr] = sv;
                }
                zacc[qtile] += (s[0] + s[1]) + (s[2] + s[3]);
                unsigned int p0 = pk_bf16(s[0], s[1]);
                unsigned int p1 = pk_bf16(s[2], s[3]);
                const int qrow = qtile * 16 + r15;
                const int k0 = ktile * 16 + g * 4;
                const int byte = qrow * 128 + (((k0 >> 3) ^ (qrow & 7)) << 4) + ((k0 & 7) * 2);
                *(unsigned int*)(ssmW + byte)     = p0;
                *(unsigned int*)(ssmW + byte + 4) = p1;
            }
        }

        // ============ convert V fragments (loads long since landed) ============
        short8 vB[2][4];
        #pragma unroll
        for (int kc = 0; kc < 2; ++kc)
            #pragma unroll
            for (int dtile = 0; dtile < 4; ++dtile) {
                #pragma unroll
                for (int p = 0; p < 4; ++p) {
                    unsigned int pk = pk_bf16(vraw[kc][dtile][2 * p], vraw[kc][dtile][2 * p + 1]);
                    vB[kc][dtile][2 * p]     = (short)(pk & 0xFFFF);
                    vB[kc][dtile][2 * p + 1] = (short)(pk >> 16);
                }
            }

        // ============ PV: Y[q][d] += S[q][32k] * V[32k][d] ============
        #pragma unroll
        for (int kc = 0; kc < 2; ++kc) {
            short8 sA[2];
            #pragma unroll
            for (int qtile = 0; qtile < 2; ++qtile) {
                const int qrow = qtile * 16 + r15;
                const int g16 = kc * 4 + g;
                sA[qtile] = *(const short8*)(ssmW + qrow * 128 + ((g16 ^ (qrow & 7)) << 4));
            }
            #pragma unroll
            for (int dtile = 0; dtile < 4; ++dtile) {
                acc[0][dtile] = __builtin_amdgcn_mfma_f32_16x16x32_bf16(sA[0], vB[kc][dtile], acc[0][dtile], 0, 0, 0);
                acc[1][dtile] = __builtin_amdgcn_mfma_f32_16x16x32_bf16(sA[1], vB[kc][dtile], acc[1][dtile], 0, 0, 0);
            }
        }

        // zacc: sum over the 4 lane-groups -> every lane has full value
        #pragma unroll
        for (int qtile = 0; qtile < 2; ++qtile) {
            float z = zacc[qtile];
            z += __shfl_xor(z, 16);
            z += __shfl_xor(z, 32);
            zacc[qtile] = z;
        }
    }

    // ---- publish partials, transposed layout: [wave][frag][lane] ----
    {
        #pragma unroll
        for (int f = 0; f < 8; ++f) {
            floatx4 a = acc[f >> 2][f & 3];
            Racc[c][f][l] = make_float4(a[0], a[1], a[2], a[3]);
        }
        if (l < 32) Zb[c][l] = (l < 16) ? zacc[0] : zacc[1];
    }
    __syncthreads();

    // ---- cross-wave reduce: wave c owns fragment f=c; stride-1 reads ----
    {
        float4 sum = make_float4(0.f, 0.f, 0.f, 0.f);
        #pragma unroll
        for (int cw = 0; cw < 8; ++cw) {
            float4 v = Racc[cw][c][l];
            sum.x += v.x; sum.y += v.y; sum.z += v.z; sum.w += v.w;
        }
        const int qtile = c >> 2, dtile = c & 3;
        const int d = dtile * 16 + r15;
        float sv[4] = {sum.x, sum.y, sum.z, sum.w};
        #pragma unroll
        for (int rr = 0; rr < 4; ++rr) {
            int q = qbase + qtile * 16 + g * 4 + rr;
            out[(size_t)(h * S_ + q) * DV + d] = sv[rr];
        }
    }
    // ---- Y_Z ----
    if (t < 32) {
        float z = 0.f;
        #pragma unroll
        for (int cw = 0; cw < 8; ++cw) z += Zb[cw][t];
        out[(size_t)(H_ * S_ * DV) + h * S_ + qbase + t] = z;
    }
}

extern "C" void kernel_launch(void* const* d_in, const int* in_sizes, int n_in,
                              void* d_out, int out_size, void* d_ws, size_t ws_size,
                              hipStream_t stream) {
    const float* Q = (const float*)d_in[0];
    const float* K = (const float*)d_in[1];
    const float* V = (const float*)d_in[2];
    // d_in[3]=M, d_in[4]=C folded into the (q.k)^2 identity; d_in[5]=continue_prev==0.
    float* out = (float*)d_out;

    taylor_fused_v6<<<128, 512, 0, stream>>>(Q, K, V, out);   // single dispatch
}